// Round 8
// baseline (1618.198 us; speedup 1.0000x reference)
//
#include <hip/hip_runtime.h>

#define NP 65536
#define EPSF 1e-12f

typedef __attribute__((ext_vector_type(8))) short s16x8;
typedef __attribute__((ext_vector_type(4))) float f32x4;

// ---- workspace layout (4B word offsets), per-batch reuse; peak 111.3 MB ----
#define OFF_PRE   0L            // qk_pre: 384*65536 = 25,165,824 floats
                                // (v-phase: v_pre at 0, vdw at +12,582,912)
#define OFF_VDW   12582912L
#define OFF_GRAMP 25165824L     // 256 rows * 4 heads * 2304 = 2,359,296
#define OFF_NQKP  27525120L     // 384 ch * 256 rows = 98,304
#define OFF_GRAM  27623424L     // 4*48*48 = 9,216
#define OFF_NRM   27632640L     // 384
#define OFF_M     27633024L     // Mpk (packed u32) 192*192 = 36,864
#define OFF_WPK   27669888L     // packed w_qkv 576*192 = 110,592
#define WS_NEED_FLOATS 27780480L
// = 111,121,920 bytes (<= round-3-proven 121.3 MB)

// ---------------------------------------------------------------------------
// split-bf16 pack: u32 = (bf16_rne(x) << 16) | bf16_rne(x - hi)
// ---------------------------------------------------------------------------
__device__ inline unsigned bf16rne(float x) {
    unsigned u = __float_as_uint(x);
    return (u + 0x7fffu + ((u >> 16) & 1u)) >> 16;
}
__device__ inline unsigned pksplit(float x) {
    unsigned h = bf16rne(x);
    unsigned hif = h << 16;
    float r = x - __uint_as_float(hif);
    unsigned l = bf16rne(r) & 0xffffu;
    return hif | l;
}
// unpack 8 packed u32 (2x uint4) -> hi frag + lo frag (8 bf16 each)
__device__ inline void unpack8(uint4 p0, uint4 p1, s16x8& h, s16x8& l) {
    union { unsigned u[4]; s16x8 v; } H, L;
    H.u[0] = __builtin_amdgcn_perm(p0.y, p0.x, 0x07060302);
    H.u[1] = __builtin_amdgcn_perm(p0.w, p0.z, 0x07060302);
    H.u[2] = __builtin_amdgcn_perm(p1.y, p1.x, 0x07060302);
    H.u[3] = __builtin_amdgcn_perm(p1.w, p1.z, 0x07060302);
    L.u[0] = __builtin_amdgcn_perm(p0.y, p0.x, 0x05040100);
    L.u[1] = __builtin_amdgcn_perm(p0.w, p0.z, 0x05040100);
    L.u[2] = __builtin_amdgcn_perm(p1.y, p1.x, 0x05040100);
    L.u[3] = __builtin_amdgcn_perm(p1.w, p1.z, 0x05040100);
    h = H.v; l = L.v;
}

// ---------------------------------------------------------------------------
// pack weights once per launch: wpk[i] = pksplit(w[i])
// ---------------------------------------------------------------------------
__global__ __launch_bounds__(256) void packw_k(
    const float* __restrict__ w, unsigned* __restrict__ wpk, int n)
{
    int i = blockIdx.x * 256 + threadIdx.x;
    if (i < n) wpk[i] = pksplit(w[i]);
}

// ---------------------------------------------------------------------------
// Split-bf16 MFMA GEMM: Out(f32) = A(packed u32 [OC][192]) @ X(f32 [192][NP]).
// Block 64oc x 256px, 4 waves (each 64oc x 64px), acc[4][4] f32x4.
// K-loop 6 steps of 32. A staged packed; X packed on the fly (transposed in
// LDS so B-frag reads are k-contiguous b128). 3 MFMA per product (AhXh,
// AhXl, AlXh); AlXl dropped (~2^-18 rel). Layouts: A[l&15][(l>>4)*8+i],
// B[(l>>4)*8+i][l&15], C/D col=l&15,row=(l>>4)*4+r (m89/m91-verified).
// ---------------------------------------------------------------------------
__global__ __launch_bounds__(256) void gemm_split(
    const unsigned* __restrict__ Apk,
    const float* __restrict__ X,
    float* __restrict__ Out)
{
    __shared__ unsigned As[64][36];    // 9.2 KB  (row stride 144B, 16B-aligned)
    __shared__ unsigned Xs[256][36];   // 36.9 KB (transposed: [px][k])

    const int t = threadIdx.x;
    const int px0 = blockIdx.x * 256;
    const int oc0 = blockIdx.y * 64;
    const int w = t >> 6;
    const int l = t & 63;
    const int lr = l & 15;
    const int lq = l >> 4;

    f32x4 acc[4][4];
    #pragma unroll
    for (int m = 0; m < 4; m++)
        #pragma unroll
        for (int n = 0; n < 4; n++)
            acc[m][n] = (f32x4){0.f, 0.f, 0.f, 0.f};

    for (int ks = 0; ks < 6; ks++) {
        const int k0 = ks * 32;
        __syncthreads();
        { // stage A tile: 64 rows x 32 packed u32
            const int row = t >> 2, ch = (t & 3) * 8;
            const unsigned* gp = Apk + (long)(oc0 + row) * 192 + k0 + ch;
            uint4 a0 = *(const uint4*)gp;
            uint4 a1 = *(const uint4*)(gp + 4);
            *(uint4*)&As[row][ch] = a0;
            *(uint4*)&As[row][ch + 4] = a1;
        }
        { // stage X tile: thread t owns px_local = t; pack 32 k-values
            const float* xp = X + (long)k0 * NP + px0 + t;
            #pragma unroll
            for (int j4 = 0; j4 < 8; j4++) {
                uint4 v;
                v.x = pksplit(xp[(long)(j4 * 4 + 0) * NP]);
                v.y = pksplit(xp[(long)(j4 * 4 + 1) * NP]);
                v.z = pksplit(xp[(long)(j4 * 4 + 2) * NP]);
                v.w = pksplit(xp[(long)(j4 * 4 + 3) * NP]);
                *(uint4*)&Xs[t][j4 * 4] = v;
            }
        }
        __syncthreads();
        // A fragments for the 4 row-blocks
        s16x8 Ah[4], Al[4];
        #pragma unroll
        for (int m = 0; m < 4; m++) {
            const unsigned* ap = &As[m * 16 + lr][lq * 8];
            uint4 p0 = *(const uint4*)ap;
            uint4 p1 = *(const uint4*)(ap + 4);
            unpack8(p0, p1, Ah[m], Al[m]);
        }
        #pragma unroll
        for (int n = 0; n < 4; n++) {
            const unsigned* xp2 = &Xs[w * 64 + n * 16 + lr][lq * 8];
            uint4 p0 = *(const uint4*)xp2;
            uint4 p1 = *(const uint4*)(xp2 + 4);
            s16x8 Xh, Xl;
            unpack8(p0, p1, Xh, Xl);
            #pragma unroll
            for (int m = 0; m < 4; m++) {
                acc[m][n] = __builtin_amdgcn_mfma_f32_16x16x32_bf16(
                    Ah[m], Xh, acc[m][n], 0, 0, 0);
                acc[m][n] = __builtin_amdgcn_mfma_f32_16x16x32_bf16(
                    Ah[m], Xl, acc[m][n], 0, 0, 0);
                acc[m][n] = __builtin_amdgcn_mfma_f32_16x16x32_bf16(
                    Al[m], Xh, acc[m][n], 0, 0, 0);
            }
        }
    }
    // epilogue: C/D layout col=l&15, row=lq*4+r
    #pragma unroll
    for (int m = 0; m < 4; m++)
        #pragma unroll
        for (int n = 0; n < 4; n++) {
            float* op = Out + (long)(oc0 + m * 16 + lq * 4) * NP
                        + px0 + w * 64 + n * 16 + lr;
            #pragma unroll
            for (int r = 0; r < 4; r++)
                op[(long)r * NP] = acc[m][n][r];
        }
}

// ---------------------------------------------------------------------------
// Fused depthwise-3x3 + Gram + norms, v2 (spill-safe).  [unchanged, unmeasured]
// ---------------------------------------------------------------------------
__global__ __launch_bounds__(256, 2) void dwgram_k(
    const float* __restrict__ pre, const float* __restrict__ wdw,
    const float* __restrict__ mask,
    float* __restrict__ gramP, float* __restrict__ nqkp)
{
    const int y = blockIdx.x;
    const int h = blockIdx.y;
    const int t = threadIdx.x;
    const int g = t >> 6;
    const int u = t & 63;
    const int ti = u >> 3, tj = u & 7;

    __shared__ float qs[48][132];
    __shared__ float ks[48][132];
    __shared__ float halo[8][3][132];
    __shared__ float4 m2s4[32];

    float acc[6][6];
    #pragma unroll
    for (int a = 0; a < 6; a++)
        #pragma unroll
        for (int d = 0; d < 6; d++) acc[a][d] = 0.f;

    float nsum = 0.f;
    const int col4 = t & 31;
    const int rL = t >> 5;

    #pragma unroll 1
    for (int s = 0; s < 2; s++) {
        const int x0 = s * 128;
        if (t < 32) {
            float4 mv = *(const float4*)&mask[y * 256 + x0 + t * 4];
            m2s4[t] = make_float4(mv.x * mv.x, mv.y * mv.y,
                                  mv.z * mv.z, mv.w * mv.w);
        }
        #pragma unroll 1
        for (int grp = 0; grp < 12; grp++) {
            const int side = grp >= 6;
            const int r0 = (grp % 6) * 8;
            const int chBase = (side ? 192 : 0) + h * 48 + r0;
            __syncthreads();
            for (int idx = t; idx < 8 * 3 * 132; idx += 256) {
                const int hc = idx / 396;
                const int rem = idx - hc * 396;
                const int dy = rem / 132;
                const int col = rem - dy * 132;
                const int yy = y + dy - 1;
                const int xx = x0 + col - 1;
                float v = 0.f;
                if (yy >= 0 && yy < 256 && xx >= 0 && xx < 256)
                    v = pre[(long)(chBase + hc) * NP + yy * 256 + xx];
                halo[hc][dy][col] = v;
            }
            __syncthreads();
            {
                const int ch = chBase + rL;
                const float* wp = wdw + ch * 9;
                const int c0 = col4 * 4;
                float o0 = 0.f, o1 = 0.f, o2 = 0.f, o3 = 0.f;
                #pragma unroll
                for (int dy = 0; dy < 3; dy++) {
                    const float* hp = &halo[rL][dy][c0];
                    const float w0 = wp[dy * 3 + 0];
                    const float w1 = wp[dy * 3 + 1];
                    const float w2 = wp[dy * 3 + 2];
                    float i0 = hp[0], i1 = hp[1], i2 = hp[2];
                    float i3 = hp[3], i4 = hp[4], i5 = hp[5];
                    o0 = fmaf(i0, w0, o0); o0 = fmaf(i1, w1, o0); o0 = fmaf(i2, w2, o0);
                    o1 = fmaf(i1, w0, o1); o1 = fmaf(i2, w1, o1); o1 = fmaf(i3, w2, o1);
                    o2 = fmaf(i2, w0, o2); o2 = fmaf(i3, w1, o2); o2 = fmaf(i4, w2, o2);
                    o3 = fmaf(i3, w0, o3); o3 = fmaf(i4, w1, o3); o3 = fmaf(i5, w2, o3);
                }
                float* dst = side ? &ks[r0 + rL][c0] : &qs[r0 + rL][c0];
                *(float4*)dst = make_float4(o0, o1, o2, o3);
            }
        }
        __syncthreads();
        #pragma unroll
        for (int p = 0; p < 32; p += 4) {
            const int pp = 32 * g + p;
            const float4 m2 = m2s4[pp >> 2];
            float4 qm[6];
            #pragma unroll
            for (int a = 0; a < 6; a++) {
                float4 qv = *(const float4*)&qs[6 * ti + a][pp];
                qm[a] = make_float4(qv.x * m2.x, qv.y * m2.y,
                                    qv.z * m2.z, qv.w * m2.w);
            }
            #pragma unroll
            for (int d = 0; d < 6; d++) {
                const float4 kv = *(const float4*)&ks[6 * tj + d][pp];
                #pragma unroll
                for (int a = 0; a < 6; a++) {
                    acc[a][d] = fmaf(qm[a].x, kv.x, acc[a][d]);
                    acc[a][d] = fmaf(qm[a].y, kv.y, acc[a][d]);
                    acc[a][d] = fmaf(qm[a].z, kv.z, acc[a][d]);
                    acc[a][d] = fmaf(qm[a].w, kv.w, acc[a][d]);
                }
            }
        }
        if (t < 96) {
            const float* row = (t < 48) ? &qs[t][0] : &ks[t - 48][0];
            #pragma unroll 8
            for (int p = 0; p < 128; p += 4) {
                float4 v = *(const float4*)&row[p];
                nsum = fmaf(v.x, v.x, nsum);
                nsum = fmaf(v.y, v.y, nsum);
                nsum = fmaf(v.z, v.z, nsum);
                nsum = fmaf(v.w, v.w, nsum);
            }
        }
        __syncthreads();
    }
    if (t < 96) {
        const int gch = (t < 48) ? (h * 48 + t) : (192 + h * 48 + (t - 48));
        nqkp[gch * 256 + y] = nsum;
    }
    float* scratch = &qs[0][0];
    for (int gg = 0; gg < 4; gg++) {
        if (g == gg) {
            #pragma unroll
            for (int a = 0; a < 6; a++)
                #pragma unroll
                for (int d = 0; d < 6; d++) {
                    const int idx = (6 * ti + a) * 48 + 6 * tj + d;
                    if (gg == 0) scratch[idx] = acc[a][d];
                    else scratch[idx] += acc[a][d];
                }
        }
        __syncthreads();
    }
    float* gp = gramP + ((long)y * 4 + h) * 2304;
    for (int idx = t; idx < 2304; idx += 256) gp[idx] = scratch[idx];
}

// ---------------------------------------------------------------------------
// Depthwise 3x3 for v channels (192).
// ---------------------------------------------------------------------------
__global__ __launch_bounds__(256) void dwv_k(
    const float* __restrict__ vpre, const float* __restrict__ wdw,
    float* __restrict__ vdw)
{
    const int c = blockIdx.y;
    const int y = blockIdx.x;
    const int x = threadIdx.x;
    const float* p = vpre + (long)c * NP + y * 256 + x;
    const float* wp = wdw + (384 + c) * 9;
    float s = 0.f;
    int ii = 0;
    #pragma unroll
    for (int dy = -1; dy <= 1; dy++)
        #pragma unroll
        for (int dx = -1; dx <= 1; dx++, ii++) {
            int yy = y + dy, xx = x + dx;
            float v = (yy >= 0 && yy < 256 && xx >= 0 && xx < 256)
                          ? p[dy * 256 + dx] : 0.f;
            s = fmaf(v, wp[ii], s);
        }
    vdw[(long)c * NP + y * 256 + x] = s;
}

// ---------------------------------------------------------------------------
// Reduce partials.
// ---------------------------------------------------------------------------
__global__ __launch_bounds__(256) void reduce_k(
    const float* __restrict__ gramP, const float* __restrict__ nqkp,
    float* __restrict__ gram, float* __restrict__ nrm)
{
    int idx = blockIdx.x * 256 + threadIdx.x;
    if (idx < 9216) {
        const float* p = gramP + idx;
        float s = 0.f;
        #pragma unroll 8
        for (int blk = 0; blk < 256; blk++) s += p[(long)blk * 9216];
        gram[idx] = s;
    } else if (idx < 9600) {
        int i2 = idx - 9216;
        const float* p = nqkp + (long)i2 * 256;
        float s = 0.f;
        #pragma unroll 8
        for (int r = 0; r < 256; r++) s += p[r];
        nrm[i2] = s;
    }
}

// ---------------------------------------------------------------------------
// Softmax + Wproj fold -> Mpk (packed u32 for the MFMA out-GEMM).
// ---------------------------------------------------------------------------
__global__ __launch_bounds__(256) void finalize_k(
    const float* __restrict__ gram, const float* __restrict__ nrm,
    const float* __restrict__ wproj, const float* __restrict__ temp,
    unsigned* __restrict__ Mpk)
{
    int h = blockIdx.x;
    int t = threadIdx.x;
    __shared__ float attn[48][49];
    __shared__ float qn[48], kn[48];
    if (t < 96) {
        int c = t % 48;
        int ch = h * 48 + c;
        float v = nrm[(t < 48 ? 0 : 192) + ch];
        float s = fmaxf(sqrtf(v), EPSF);
        if (t < 48) qn[c] = s; else kn[c] = s;
    }
    __syncthreads();
    float tp = temp[h];
    for (int idx = t; idx < 2304; idx += 256) {
        int c = idx / 48, d = idx % 48;
        attn[c][d] = gram[(h * 48 + c) * 48 + d] * tp / (qn[c] * kn[d]);
    }
    __syncthreads();
    if (t < 48) {
        float mx = -1e30f;
        for (int d = 0; d < 48; d++) mx = fmaxf(mx, attn[t][d]);
        float s = 0.f;
        for (int d = 0; d < 48; d++) {
            float e = expf(attn[t][d] - mx);
            attn[t][d] = e; s += e;
        }
        float inv = 1.f / s;
        for (int d = 0; d < 48; d++) attn[t][d] *= inv;
    }
    __syncthreads();
    for (int idx = t; idx < 9216; idx += 256) {
        int o = idx / 48, d = idx % 48;
        float s = 0.f;
        #pragma unroll
        for (int c = 0; c < 48; c++)
            s = fmaf(wproj[o * 192 + h * 48 + c], attn[c][d], s);
        Mpk[o * 192 + h * 48 + d] = pksplit(s);
    }
}

// ---------------------------------------------------------------------------
extern "C" void kernel_launch(void* const* d_in, const int* in_sizes, int n_in,
                              void* d_out, int out_size, void* d_ws, size_t ws_size,
                              hipStream_t stream) {
    const float* x     = (const float*)d_in[0];
    const float* mask  = (const float*)d_in[1];
    const float* wqkv  = (const float*)d_in[2];
    const float* wdw   = (const float*)d_in[3];
    const float* wproj = (const float*)d_in[4];
    const float* temp  = (const float*)d_in[5];
    float* out = (float*)d_out;
    float* ws  = (float*)d_ws;

    if (ws_size < (size_t)WS_NEED_FLOATS * sizeof(float)) return;

    float*    pre   = ws + OFF_PRE;
    float*    vdw   = ws + OFF_VDW;
    float*    gramP = ws + OFF_GRAMP;
    float*    nqkp  = ws + OFF_NQKP;
    float*    gram  = ws + OFF_GRAM;
    float*    nrm   = ws + OFF_NRM;
    unsigned* mpk   = (unsigned*)(ws + OFF_M);
    unsigned* wpk   = (unsigned*)(ws + OFF_WPK);

    // pack weights (runs every launch; deterministic)
    packw_k<<<432, 256, 0, stream>>>(wqkv, wpk, 576 * 192);

    for (int b = 0; b < 2; b++) {
        const float* xb    = x    + (long)b * 192 * NP;
        const float* maskb = mask + (long)b * NP;
        float*       outb  = out  + (long)b * 192 * NP;

        // qk_pre = Wqk @ x[b]   (384x192 @ 192x65536, split-bf16 MFMA)
        gemm_split<<<dim3(256, 6, 1), 256, 0, stream>>>(wpk, xb, pre);
        // fused dw conv + gram + norm partials
        dwgram_k<<<dim3(256, 4, 1), 256, 0, stream>>>(
            pre, wdw, maskb, gramP, nqkp);
        // reduce partials
        reduce_k<<<38, 256, 0, stream>>>(gramP, nqkp, gram, nrm);
        // softmax + Wproj fold -> Mpk
        finalize_k<<<4, 256, 0, stream>>>(gram, nrm, wproj, temp, mpk);
        // v_pre = Wv @ x[b]  (reuses pre region)
        gemm_split<<<dim3(256, 3, 1), 256, 0, stream>>>(
            wpk + 384 * 192, xb, pre);
        // depthwise on v
        dwv_k<<<dim3(256, 192, 1), 256, 0, stream>>>(pre, wdw, vdw);
        // out[b] = M @ vdw
        gemm_split<<<dim3(256, 3, 1), 256, 0, stream>>>(mpk, vdw, outb);
    }
}